// Round 3
// baseline (103.593 us; speedup 1.0000x reference)
//
#include <hip/hip_runtime.h>
#include <cstddef>

typedef _Float16 f16;
typedef __attribute__((ext_vector_type(2))) _Float16 f16x2;
typedef __attribute__((ext_vector_type(4))) _Float16 f16x4;
typedef __attribute__((ext_vector_type(8))) _Float16 f16x8;
typedef __attribute__((ext_vector_type(4))) float fx4;

union f16x8u { f16x8 v; f16x2 h[4]; };

#define BS   2
#define NPTS 512
#define DIN  256
#define NH   8
#define DH   64
#define HD   512   // NH*DH

// ---------------------------------------------------------------------------
// K0: prep — fp32->f16 convert of x, transposed f16 copies of W, a->f16,
//     adj passthrough (as float) into second half of d_out.
// block ranges: [0,256) x convert | [256,352) W transpose | 352 a | [353,865) adj
// ---------------------------------------------------------------------------
__global__ __launch_bounds__(256) void prep_kernel(
    const float* __restrict__ x, const float* __restrict__ W0,
    const float* __restrict__ W1, const float* __restrict__ W2,
    const float* __restrict__ a, const int* __restrict__ adj,
    f16* __restrict__ x16, f16* __restrict__ Wt16, f16* __restrict__ a16,
    float* __restrict__ out_adj)
{
    const int blk = blockIdx.x;
    const int t = threadIdx.x;
    if (blk < 256) {
        // x: 2*512*256 = 262144 f32 -> f16, 1024 per block
        int idx = blk * 1024 + t * 4;
        float4 v = *(const float4*)(x + idx);
        f16x4 h = {(f16)v.x, (f16)v.y, (f16)v.z, (f16)v.w};
        *(f16x4*)(x16 + idx) = h;
    } else if (blk < 352) {
        // W (256x512) -> Wt16 (512x256) f16, 64x64 tiles, 32 tiles per W
        __shared__ float lds[64][65];
        int idx = blk - 256;
        int w = idx >> 5;          // which W
        int tile = idx & 31;
        int k0 = (tile >> 3) * 64, n0 = (tile & 7) * 64;
        const float* W = (w == 0) ? W0 : ((w == 1) ? W1 : W2);
        int r = t >> 2;            // 0..63
        int cg = (t & 3) * 16;     // 0,16,32,48
        #pragma unroll
        for (int i = 0; i < 4; ++i) {
            float4 v = *(const float4*)(W + (size_t)(k0 + r) * HD + n0 + cg + i * 4);
            lds[r][cg + i * 4 + 0] = v.x;
            lds[r][cg + i * 4 + 1] = v.y;
            lds[r][cg + i * 4 + 2] = v.z;
            lds[r][cg + i * 4 + 3] = v.w;
        }
        __syncthreads();
        f16* dst = Wt16 + (size_t)w * (HD * DIN) + (size_t)(n0 + r) * DIN + k0 + cg;
        #pragma unroll
        for (int i = 0; i < 16; ++i) dst[i] = (f16)lds[cg + i][r];
    } else if (blk == 352) {
        for (int i = t; i < NH * DH; i += 256) a16[i] = (f16)a[i];
    } else {
        // adj passthrough: 2*512*512 = 524288 ints -> float, 1024 per block
        int idx = (blk - 353) * 1024 + t * 4;
        int4 v = *(const int4*)(adj + idx);
        float4 fv = {(float)v.x, (float)v.y, (float)v.z, (float)v.w};
        *(float4*)(out_adj + idx) = fv;
    }
}

// ---------------------------------------------------------------------------
// K1: 3 projections via MFMA f16.  A = x16 (1024x256), B^T = Wt16 (512x256).
// grid (16 Mtiles, 8 Ntiles, 3 weights), block 256 (4 waves), block tile 64x64.
// z=0: src (writes src16 [b][h][n][d] + srcT16 [b][h][d][n])
// z=1: tgt (tgt16 [b][h][m][d]);  z=2: skip (f32 [b][n][h*64+d])
// ---------------------------------------------------------------------------
__global__ __launch_bounds__(256) void proj_kernel(
    const f16* __restrict__ x16, const f16* __restrict__ Wt16,
    f16* __restrict__ src16, f16* __restrict__ srcT16, f16* __restrict__ tgt16,
    float* __restrict__ skipf)
{
    __shared__ f16 Alds[64 * 136];   // 64 rows x 128 k, pad to 136
    __shared__ f16 Blds[64 * 136];
    const int t = threadIdx.x;
    const int mt = blockIdx.x, nt = blockIdx.y, wz = blockIdx.z;
    const f16* Wt = Wt16 + (size_t)wz * (HD * DIN);
    const int lane = t & 63, wv = t >> 6;
    const int l15 = lane & 15, quad = lane >> 4;
    const int moff = (wv & 1) * 32, noff = (wv >> 1) * 32;

    fx4 acc[2][2];
    #pragma unroll
    for (int fi = 0; fi < 2; ++fi)
        #pragma unroll
        for (int fj = 0; fj < 2; ++fj)
            acc[fi][fj] = (fx4){0.f, 0.f, 0.f, 0.f};

    for (int kk = 0; kk < 2; ++kk) {
        if (kk) __syncthreads();
        // stage 64 rows x 128 k per buffer = 1024 f16x8 chunks; 256 thr x 4
        #pragma unroll
        for (int i = 0; i < 4; ++i) {
            int idx = t + i * 256;
            int row = idx >> 4, seg = idx & 15;
            *(f16x8*)&Alds[row * 136 + seg * 8] =
                *(const f16x8*)(x16 + (size_t)(mt * 64 + row) * DIN + kk * 128 + seg * 8);
            *(f16x8*)&Blds[row * 136 + seg * 8] =
                *(const f16x8*)(Wt + (size_t)(nt * 64 + row) * DIN + kk * 128 + seg * 8);
        }
        __syncthreads();
        #pragma unroll
        for (int ks = 0; ks < 4; ++ks) {
            f16x8 aF[2], bF[2];
            #pragma unroll
            for (int f = 0; f < 2; ++f) {
                aF[f] = *(const f16x8*)&Alds[(moff + f * 16 + l15) * 136 + ks * 32 + quad * 8];
                bF[f] = *(const f16x8*)&Blds[(noff + f * 16 + l15) * 136 + ks * 32 + quad * 8];
            }
            #pragma unroll
            for (int fi = 0; fi < 2; ++fi)
                #pragma unroll
                for (int fj = 0; fj < 2; ++fj)
                    acc[fi][fj] = __builtin_amdgcn_mfma_f32_16x16x32_f16(
                        aF[fi], bF[fj], acc[fi][fj], 0, 0, 0);
        }
    }

    // epilogue: C/D layout col=lane&15, row=quad*4+reg
    #pragma unroll
    for (int fi = 0; fi < 2; ++fi)
        #pragma unroll
        for (int fj = 0; fj < 2; ++fj)
            #pragma unroll
            for (int i = 0; i < 4; ++i) {
                int rowg = mt * 64 + moff + fi * 16 + quad * 4 + i;  // 0..1023 = b*512+n
                int colg = nt * 64 + noff + fj * 16 + l15;           // 0..511  = h*64+d
                float v = acc[fi][fj][i];
                if (wz == 2) {
                    skipf[(size_t)rowg * HD + colg] = v;
                } else {
                    int bb = rowg >> 9, n = rowg & 511;
                    int hh = colg >> 6, d = colg & 63;
                    size_t bh = (size_t)bb * NH + hh;
                    if (wz == 0) {
                        src16[(bh * NPTS + n) * DH + d] = (f16)v;
                        srcT16[(bh * DH + d) * NPTS + n] = (f16)v;
                    } else {
                        tgt16[(bh * NPTS + n) * DH + d] = (f16)v;
                    }
                }
            }
}

// ---------------------------------------------------------------------------
// K2: fused attention.  grid (32 row-tiles, 8 h, 2 b), block 256 (4 waves).
// Block = 16 rows x all 512 m for one (b,h).  Wave owns 4 rows.
// Phase 1: scores via packed-f16 VALU (leaky(s+t)·a, f32 accum via v_dot2),
//          masked raw scores -> p_lds (f16).
// Phase 2: softmax per row (64-lane shfl reductions), normalize in p_lds.
// Phase 3: PV via MFMA f16 (A from p_lds, B from srcT16 in L2).
// Phase 4: + skip + bias, ELU, store.
// ---------------------------------------------------------------------------
__global__ __launch_bounds__(256) void attn_kernel(
    const f16* __restrict__ src16, const f16* __restrict__ srcT16,
    const f16* __restrict__ tgt16, const f16* __restrict__ a16,
    const float* __restrict__ skipf, const float* __restrict__ bias,
    const int* __restrict__ adj, float* __restrict__ out)
{
    __shared__ f16 tgt_lds[256 * 72];   // 36.9 KB, stride 72 (36 dw ≡ 4 mod 32)
    __shared__ f16 p_lds[16 * 520];     // 16.6 KB, stride 520 (260 dw ≡ 4 mod 32)
    __shared__ f16 src_lds[16 * 64];    // 2 KB (broadcast reads only)
    __shared__ f16 a_lds[64];

    const int t = threadIdx.x;
    const int lane = t & 63, wv = t >> 6;
    const int n0 = blockIdx.x * 16;
    const int h = blockIdx.y, b = blockIdx.z;
    const int bh = b * NH + h;
    const f16x2 slope2 = {(f16)0.2f, (f16)0.2f};

    // stage src rows (16x64) + a (64) once
    if (t < 128) {
        int row = t >> 3, seg = t & 7;
        *(f16x8*)&src_lds[row * 64 + seg * 8] =
            *(const f16x8*)(src16 + ((size_t)bh * NPTS + n0 + row) * DH + seg * 8);
    } else if (t < 136) {
        int seg = t - 128;
        *(f16x8*)&a_lds[seg * 8] = *(const f16x8*)(a16 + h * DH + seg * 8);
    }

    const int r0 = n0 + wv * 4;

    for (int mtile = 0; mtile < 2; ++mtile) {
        __syncthreads();
        // stage tgt tile: 256 rows x 64 d = 2048 f16x8 chunks; 256 thr x 8
        #pragma unroll
        for (int i = 0; i < 8; ++i) {
            int idx = t + i * 256;
            int row = idx >> 3, seg = idx & 7;
            *(f16x8*)&tgt_lds[row * 72 + seg * 8] =
                *(const f16x8*)(tgt16 + ((size_t)bh * NPTS + mtile * 256 + row) * DH + seg * 8);
        }
        __syncthreads();

        float sc[4][4] = {{0.f, 0.f, 0.f, 0.f}, {0.f, 0.f, 0.f, 0.f},
                          {0.f, 0.f, 0.f, 0.f}, {0.f, 0.f, 0.f, 0.f}};
        for (int st = 0; st < 8; ++st) {   // 8 d-chunks of 8
            f16x8u a8; a8.v = *(const f16x8*)&a_lds[st * 8];
            f16x8u s8[4];
            #pragma unroll
            for (int r = 0; r < 4; ++r)
                s8[r].v = *(const f16x8*)&src_lds[(wv * 4 + r) * 64 + st * 8];
            #pragma unroll
            for (int jj = 0; jj < 4; ++jj) {
                int ml = jj * 64 + lane;
                f16x8u t8; t8.v = *(const f16x8*)&tgt_lds[ml * 72 + st * 8];
                #pragma unroll
                for (int c = 0; c < 4; ++c) {
                    f16x2 t2 = t8.h[c];
                    f16x2 a2 = a8.h[c];
                    #pragma unroll
                    for (int r = 0; r < 4; ++r) {
                        f16x2 z = s8[r].h[c] + t2;
                        f16x2 zl = __builtin_elementwise_max(z, z * slope2);
                        sc[r][jj] = __builtin_amdgcn_fdot2(a2, zl, sc[r][jj], false);
                    }
                }
            }
        }
        // mask + store raw f16 scores
        #pragma unroll
        for (int r = 0; r < 4; ++r) {
            #pragma unroll
            for (int jj = 0; jj < 4; ++jj) {
                int m = mtile * 256 + jj * 64 + lane;
                int av = adj[((size_t)b * NPTS + r0 + r) * NPTS + m];
                float s = (av > 0) ? sc[r][jj] : -1e30f;   // f16 -> -inf, exp -> 0
                p_lds[(wv * 4 + r) * 520 + m] = (f16)s;
            }
        }
    }
    __syncthreads();

    // softmax: wave wv owns rows wv*4 .. wv*4+3; each lane holds 8 scores
    #pragma unroll
    for (int r = 0; r < 4; ++r) {
        int row = wv * 4 + r;
        f16x8 v = *(const f16x8*)&p_lds[row * 520 + lane * 8];
        float vf[8];
        #pragma unroll
        for (int i = 0; i < 8; ++i) vf[i] = (float)v[i];
        float mx = vf[0];
        #pragma unroll
        for (int i = 1; i < 8; ++i) mx = fmaxf(mx, vf[i]);
        for (int msk = 1; msk < 64; msk <<= 1) mx = fmaxf(mx, __shfl_xor(mx, msk, 64));
        float l = 0.f;
        #pragma unroll
        for (int i = 0; i < 8; ++i) { vf[i] = __expf(vf[i] - mx); l += vf[i]; }
        for (int msk = 1; msk < 64; msk <<= 1) l += __shfl_xor(l, msk, 64);
        float inv = 1.0f / l;
        f16x8 pv;
        #pragma unroll
        for (int i = 0; i < 8; ++i) pv[i] = (f16)(vf[i] * inv);
        *(f16x8*)&p_lds[row * 520 + lane * 8] = pv;
    }
    __syncthreads();

    // PV via MFMA: wave wv handles d-range [wv*16, wv*16+16), all 16 rows
    const int l15 = lane & 15, quad = lane >> 4;
    fx4 acc = {0.f, 0.f, 0.f, 0.f};
    const f16* vb = srcT16 + ((size_t)bh * DH + wv * 16 + l15) * NPTS;
    #pragma unroll
    for (int ks = 0; ks < 16; ++ks) {
        f16x8 a8 = *(const f16x8*)&p_lds[l15 * 520 + ks * 32 + quad * 8];
        f16x8 b8 = *(const f16x8*)(vb + ks * 32 + quad * 8);
        acc = __builtin_amdgcn_mfma_f32_16x16x32_f16(a8, b8, acc, 0, 0, 0);
    }
    // epilogue: + skip + bias, ELU
    #pragma unroll
    for (int i = 0; i < 4; ++i) {
        int ng = n0 + quad * 4 + i;
        int col = h * DH + wv * 16 + l15;
        size_t oi = ((size_t)b * NPTS + ng) * HD + col;
        float val = acc[i] + skipf[oi] + bias[col];
        out[oi] = (val > 0.f) ? val : __expf(val) - 1.f;
    }
}

// ---------------------------------------------------------------------------
extern "C" void kernel_launch(void* const* d_in, const int* in_sizes, int n_in,
                              void* d_out, int out_size, void* d_ws, size_t ws_size,
                              hipStream_t stream) {
    const float* x     = (const float*)d_in[0];
    const int*   adj   = (const int*)d_in[1];
    const float* Wsrc  = (const float*)d_in[2];
    const float* Wtgt  = (const float*)d_in[3];
    const float* Wskip = (const float*)d_in[4];
    const float* a     = (const float*)d_in[5];
    const float* bias  = (const float*)d_in[6];

    float* out = (float*)d_out;                       // 524288 f32 (bs,n,H*d)
    float* out_adj = out + (size_t)BS * NPTS * NPTS;  // adj echoed as float

    char* wsb = (char*)d_ws;
    f16*   src16  = (f16*)(wsb + 0x000000);           // 1 MB  [b][h][n][d]
    f16*   srcT16 = (f16*)(wsb + 0x100000);           // 1 MB  [b][h][d][n]
    f16*   tgt16  = (f16*)(wsb + 0x200000);           // 1 MB  [b][h][m][d]
    f16*   x16    = (f16*)(wsb + 0x300000);           // 512 KB
    f16*   Wt16   = (f16*)(wsb + 0x380000);           // 768 KB (3 x 512x256)
    f16*   a16    = (f16*)(wsb + 0x440000);           // 1 KB
    float* skipf  = (float*)(wsb + 0x480000);         // 2 MB  [b*n][h*64+d]

    prep_kernel<<<865, 256, 0, stream>>>(x, Wsrc, Wtgt, Wskip, a, adj,
                                         x16, Wt16, a16, out_adj);
    proj_kernel<<<dim3(16, 8, 3), 256, 0, stream>>>(x16, Wt16, src16, srcT16,
                                                    tgt16, skipf);
    attn_kernel<<<dim3(32, 8, 2), 256, 0, stream>>>(src16, srcT16, tgt16, a16,
                                                    skipf, bias, adj, out);
}